// Round 15
// baseline (4759.602 us; speedup 1.0000x reference)
//
#include <hip/hip_runtime.h>

typedef _Float16 f16;
typedef __attribute__((ext_vector_type(4))) _Float16 f16x4;
typedef __attribute__((ext_vector_type(8))) _Float16 f16x8;
typedef __attribute__((ext_vector_type(4))) float f32x4;
typedef __attribute__((ext_vector_type(4))) int i32x4;

#define D_  512
#define NH_ 8
#define NS_ 4096
#define TT_ 512
#define BB_ 4
#define VV_ 8192
#define HN_ 32768
#define BT_ 2048

// ===================== shared GEMM core (round-6 verified, FROZEN) ==========
// C(128x128) = A(128xK) * B(128xK)^T ; 256 thr = 4 waves 2x2, 4x4 frags of
// 16x16x32 MFMA.  sync; stage(global_load_lds 16B, src chunk g^(row&7),
// linear LDS dest); sync; compute(XOR'd ds_read_b128).  LDS 32KB, 0 conflicts.
// R15: operands SWAPPED at every call site (A = N-side, B = token-side) so
// each lane's r-quad = 4 consecutive output-contiguous elements -> vector
// epilogues (f16x4 stores, in-lane rope, no shuffles).  Core untouched.
// Exhausted: dbuf64K(R7), bounds5(R8), 128x256(R9), A-direct(R10),
// 256sq(R11), splitK(R12), dbuf-BK32(R13).

__device__ __forceinline__ void gl16(const void* g, void* l) {
  __builtin_amdgcn_global_load_lds((const __attribute__((address_space(1))) void*)g,
                                   (__attribute__((address_space(3))) void*)l, 16, 0, 0);
}

__device__ __forceinline__ void gemm_core(const f16* __restrict__ A, const f16* __restrict__ B,
    int lda, int ldb, int nk, char* As, char* Bs, f32x4 acc[4][4]) {
  int tid = threadIdx.x;
  int l = tid & 63, wid = tid >> 6;
  int wm = wid >> 1, wn = wid & 1;
  int row0 = tid >> 3, g0 = tid & 7;
  for (int kt = 0; kt < nk; ++kt) {
    __syncthreads();                       // prev tile fully consumed
#pragma unroll
    for (int it = 0; it < 4; ++it) {
      int row = row0 + 32 * it;
      int gs = g0 ^ (row & 7);             // inverse-swizzled source chunk
      int wb = (wid * 64 + it * 256) * 16; // wave-uniform linear LDS base
      gl16(A + (size_t)row * lda + gs * 8, As + wb);
      gl16(B + (size_t)row * ldb + gs * 8, Bs + wb);
    }
    __syncthreads();                       // vmcnt(0)+lgkm drain + barrier
    A += 64; B += 64;
#pragma unroll
    for (int kh = 0; kh < 2; ++kh) {
      f16x8 af[4], bfr[4];
#pragma unroll
      for (int m = 0; m < 4; ++m) {
        int row = wm * 64 + m * 16 + (l & 15);
        af[m] = *(const f16x8*)(As + row * 128 + ((kh * 64 + (l >> 4) * 16) ^ ((row & 7) << 4)));
      }
#pragma unroll
      for (int n = 0; n < 4; ++n) {
        int row = wn * 64 + n * 16 + (l & 15);
        bfr[n] = *(const f16x8*)(Bs + row * 128 + ((kh * 64 + (l >> 4) * 16) ^ ((row & 7) << 4)));
      }
#pragma unroll
      for (int m = 0; m < 4; ++m)
#pragma unroll
        for (int n = 0; n < 4; ++n)
          acc[m][n] = __builtin_amdgcn_mfma_f32_16x16x32_f16(af[m], bfr[n], acc[m][n], 0, 0, 0);
    }
  }
}

// ===================== GEMM wrappers (swapped operands, vector epilogues) ===

// 1) qr = rope(relu(xi @ enc)).  nwg = 4096.  A = encT rows nn, B = xi rows t.
__global__ __launch_bounds__(256, 4) void k_gemm_xs(
    const f16* __restrict__ xi, const f16* __restrict__ encT,
    const f16* __restrict__ csT, f16* __restrict__ qr) {
  __shared__ i32x4 As4[1024], Bs4[1024];
  int bid = blockIdx.x;
  int swz = (bid & 7) * 512 + (bid >> 3);
  int mt = swz & 15, nt = (swz >> 4) & 31, h = swz >> 9;
  const f16* A = encT + ((size_t)h * NS_ + nt * 128) * D_;
  const f16* B = xi + (size_t)mt * 128 * D_;
  f32x4 acc[4][4] = {};
  gemm_core(A, B, D_, D_, D_ / 64, (char*)As4, (char*)Bs4, acc);
  int l = threadIdx.x & 63, wid = threadIdx.x >> 6;
  int wm = wid >> 1, wn = wid & 1;
  int r04 = (l >> 4) * 4, c0 = l & 15;
  int b = (mt * 128) >> 9;
  int tbase = (mt * 128) & (TT_ - 1);
#pragma unroll
  for (int m = 0; m < 4; ++m)
#pragma unroll
    for (int n = 0; n < 4; ++n) {
      int nn0 = nt * 128 + wm * 64 + m * 16 + r04;     // quad-aligned
      int t = tbase + wn * 64 + n * 16 + c0;
      f16x8 cs = *(const f16x8*)(csT + 2 * ((size_t)t * NS_ + nn0));
      f32x4 a = acc[m][n];
      float x0 = fmaxf(a[0], 0.f), x1 = fmaxf(a[1], 0.f);
      float x2 = fmaxf(a[2], 0.f), x3 = fmaxf(a[3], 0.f);
      f16x4 q;
      q[0] = (f16)(x0 * (float)cs[0] - x1 * (float)cs[1]);
      q[1] = (f16)(x1 * (float)cs[2] + x0 * (float)cs[3]);
      q[2] = (f16)(x2 * (float)cs[4] - x3 * (float)cs[5]);
      q[3] = (f16)(x3 * (float)cs[6] + x2 * (float)cs[7]);
      *(f16x4*)(qr + (((size_t)b * NH_ + h) * TT_ + t) * NS_ + nn0) = q;
    }
}

// 2) scores = tril_strict(QR @ QR^T) * N^-0.5.  nwg = 320.
//    A = qr s-block (nt), B = qr t-block (mt) -> acc[s][t].
__global__ __launch_bounds__(256, 4) void k_gemm_scores(
    const f16* __restrict__ qr, f16* __restrict__ scores) {
  __shared__ i32x4 As4[1024], Bs4[1024];
  int bid = blockIdx.x;
  int swz = (bid & 7) * 40 + (bid >> 3);
  int x = swz % 10, z = swz / 10;
  int mt = (x >= 6) ? 3 : (x >= 3) ? 2 : (x >= 1) ? 1 : 0;
  int nt = x - mt * (mt + 1) / 2;
  const f16* base = qr + (size_t)z * TT_ * NS_;
  const f16* A = base + (size_t)nt * 128 * NS_;
  const f16* B = base + (size_t)mt * 128 * NS_;
  f32x4 acc[4][4] = {};
  gemm_core(A, B, NS_, NS_, NS_ / 64, (char*)As4, (char*)Bs4, acc);
  int l = threadIdx.x & 63, wid = threadIdx.x >> 6;
  int wm = wid >> 1, wn = wid & 1;
  int r04 = (l >> 4) * 4, c0 = l & 15;
  f16* outp = scores + (size_t)z * TT_ * TT_;
#pragma unroll
  for (int m = 0; m < 4; ++m)
#pragma unroll
    for (int n = 0; n < 4; ++n) {
      int s0 = nt * 128 + wm * 64 + m * 16 + r04;
      int t = mt * 128 + wn * 64 + n * 16 + c0;
      f32x4 a = acc[m][n];
      f16x4 q;
#pragma unroll
      for (int r = 0; r < 4; ++r)
        q[r] = (f16)((t > s0 + r) ? a[r] * 0.015625f : 0.f);
      *(f16x4*)(outp + (size_t)t * TT_ + s0) = q;
    }
}

// 3) attn = scores @ xi (via xiT), f16 out.  nwg = 512, K-tiles = 2*mt+2.
//    A = xiT d-block, B = scores t-block -> acc[d][t].
__global__ __launch_bounds__(256, 4) void k_gemm_attn(
    const f16* __restrict__ scores, const f16* __restrict__ xiT, f16* __restrict__ attn) {
  __shared__ i32x4 As4[1024], Bs4[1024];
  int bid = blockIdx.x;
  int swz = (bid & 7) * 64 + (bid >> 3);
  int mt = swz & 3, ntd = (swz >> 2) & 3, z = swz >> 4;
  int b = z >> 3;
  const f16* A = xiT + (size_t)b * D_ * TT_ + (size_t)ntd * 128 * TT_;
  const f16* B = scores + (size_t)z * TT_ * TT_ + (size_t)mt * 128 * TT_;
  f32x4 acc[4][4] = {};
  gemm_core(A, B, TT_, TT_, 2 * mt + 2, (char*)As4, (char*)Bs4, acc);
  int l = threadIdx.x & 63, wid = threadIdx.x >> 6;
  int wm = wid >> 1, wn = wid & 1;
  int r04 = (l >> 4) * 4, c0 = l & 15;
#pragma unroll
  for (int m = 0; m < 4; ++m)
#pragma unroll
    for (int n = 0; n < 4; ++n) {
      int d0 = ntd * 128 + wm * 64 + m * 16 + r04;
      int t = mt * 128 + wn * 64 + n * 16 + c0;
      f32x4 a = acc[m][n];
      f16x4 q;
#pragma unroll
      for (int r = 0; r < 4; ++r) q[r] = (f16)a[r];
      *(f16x4*)(attn + ((size_t)z * TT_ + t) * D_ + d0) = q;
    }
}

// 4) xy = xs * relu(yKV @ enc_v); xs via inverse rope from qr, in-place RMW.
//    nwg = 4096, h-pinned XCD.  A = encvT rows nn, B = ykv rows t -> acc[nn][t].
__global__ __launch_bounds__(256, 4) void k_gemm_xy(
    const f16* __restrict__ ykv, const f16* __restrict__ encvT,
    const f16* __restrict__ csT, f16* __restrict__ qrxy) {
  __shared__ i32x4 As4[1024], Bs4[1024];
  int bid = blockIdx.x;
  int xcd = bid & 7, k = bid >> 3;            // k in 0..511
  int h = xcd, b = k >> 7, nt = (k >> 2) & 31, mt = k & 3;
  int z = b * NH_ + h;
  const f16* A = encvT + ((size_t)h * NS_ + nt * 128) * D_;
  const f16* B = ykv + (size_t)z * TT_ * D_ + (size_t)mt * 128 * D_;
  f32x4 acc[4][4] = {};
  gemm_core(A, B, D_, D_, D_ / 64, (char*)As4, (char*)Bs4, acc);
  int l = threadIdx.x & 63, wid = threadIdx.x >> 6;
  int wm = wid >> 1, wn = wid & 1;
  int r04 = (l >> 4) * 4, c0 = l & 15;
#pragma unroll
  for (int m = 0; m < 4; ++m)
#pragma unroll
    for (int n = 0; n < 4; ++n) {
      int nn0 = nt * 128 + wm * 64 + m * 16 + r04;
      int t = mt * 128 + wn * 64 + n * 16 + c0;
      size_t o = ((size_t)z * TT_ + t) * NS_ + nn0;
      f16x4 q4 = *(const f16x4*)(qrxy + o);
      f16x8 cs = *(const f16x8*)(csT + 2 * ((size_t)t * NS_ + nn0));
      f32x4 a = acc[m][n];
      float qe0 = (float)q4[0], qo0 = (float)q4[1];
      float qe1 = (float)q4[2], qo1 = (float)q4[3];
      float xe0 = qe0 * (float)cs[0] + qo0 * (float)cs[1];
      float xo0 = qo0 * (float)cs[2] - qe0 * (float)cs[3];
      float xe1 = qe1 * (float)cs[4] + qo1 * (float)cs[5];
      float xo1 = qo1 * (float)cs[6] - qe1 * (float)cs[7];
      f16x4 outv;
      outv[0] = (f16)(xe0 * fmaxf(a[0], 0.f));
      outv[1] = (f16)(xo0 * fmaxf(a[1], 0.f));
      outv[2] = (f16)(xe1 * fmaxf(a[2], 0.f));
      outv[3] = (f16)(xo1 * fmaxf(a[3], 0.f));
      *(f16x4*)(qrxy + o) = outv;
    }
}

// 5) ypart[kz] = xy_kz @ dec_kz (K split by head), f16.  nwg = 512.
//    A = decT c-block, B = xy t-block -> acc[c][R].
__global__ __launch_bounds__(256, 4) void k_gemm_ydec(
    const f16* __restrict__ xy, const f16* __restrict__ decT, f16* __restrict__ ypart) {
  __shared__ i32x4 As4[1024], Bs4[1024];
  int bid = blockIdx.x;
  int swz = (bid & 7) * 64 + (bid >> 3);
  int mt = swz & 15, nt = (swz >> 4) & 3, kz = swz >> 6;
  int b = mt >> 2, t0 = (mt & 3) * 128;
  const f16* A = decT + (size_t)nt * 128 * HN_ + (size_t)kz * NS_;
  const f16* B = xy + ((size_t)(b * NH_ + kz) * TT_ + t0) * NS_;
  f32x4 acc[4][4] = {};
  gemm_core(A, B, HN_, NS_, NS_ / 64, (char*)As4, (char*)Bs4, acc);
  int l = threadIdx.x & 63, wid = threadIdx.x >> 6;
  int wm = wid >> 1, wn = wid & 1;
  int r04 = (l >> 4) * 4, c0 = l & 15;
  f16* outp = ypart + (size_t)kz * BT_ * D_;
#pragma unroll
  for (int m = 0; m < 4; ++m)
#pragma unroll
    for (int n = 0; n < 4; ++n) {
      int cc0 = nt * 128 + wm * 64 + m * 16 + r04;
      int R = mt * 128 + wn * 64 + n * 16 + c0;
      f32x4 a = acc[m][n];
      f16x4 q;
#pragma unroll
      for (int r = 0; r < 4; ++r) q[r] = (f16)a[r];
      *(f16x4*)(outp + (size_t)R * D_ + cc0) = q;
    }
}

// 6) logits = zH @ lm_head.  nwg = 1024.  A = lmT v-block, B = zH -> acc[v][R].
__global__ __launch_bounds__(256, 4) void k_gemm_logits(
    const f16* __restrict__ zbf, const f16* __restrict__ lmT, float* __restrict__ outp) {
  __shared__ i32x4 As4[1024], Bs4[1024];
  int bid = blockIdx.x;
  int swz = (bid & 7) * 128 + (bid >> 3);
  int mt = swz & 15, nt = swz >> 4;
  const f16* A = lmT + (size_t)nt * 128 * D_;
  const f16* B = zbf + (size_t)mt * 128 * D_;
  f32x4 acc[4][4] = {};
  gemm_core(A, B, D_, D_, D_ / 64, (char*)As4, (char*)Bs4, acc);
  int l = threadIdx.x & 63, wid = threadIdx.x >> 6;
  int wm = wid >> 1, wn = wid & 1;
  int r04 = (l >> 4) * 4, c0 = l & 15;
#pragma unroll
  for (int m = 0; m < 4; ++m)
#pragma unroll
    for (int n = 0; n < 4; ++n) {
      int v0 = nt * 128 + wm * 64 + m * 16 + r04;
      int R = mt * 128 + wn * 64 + n * 16 + c0;
      *(f32x4*)(outp + (size_t)R * VV_ + v0) = acc[m][n];
    }
}

// ===================== LN / elementwise (wave-per-row, vectorized) ==========

__device__ __forceinline__ float wave_sum(float v) {
#pragma unroll
  for (int o = 32; o > 0; o >>= 1) v += __shfl_xor(v, o);
  return v;
}

__global__ __launch_bounds__(256) void k_tables(f16* __restrict__ csT) {
  int i = blockIdx.x * 256 + threadIdx.x;
  int t = i >> 12, n = i & (NS_ - 1);
  float q = (float)(n & ~1);
  float freq = exp2f(-16.f * q / 4096.f) * 0.15915494309189535f; // 1/(2pi)
  float ph = (float)t * freq;
  ph -= floorf(ph);
  float ang = ph * 6.283185307179586f;
  csT[2 * i]     = (f16)cosf(ang);
  csT[2 * i + 1] = (f16)sinf(ang);
}

__global__ void k_transpose(const float* __restrict__ in, f16* __restrict__ outp, int R, int C) {
  __shared__ float tile[32][33];
  size_t mo = (size_t)blockIdx.z * R * C;
  in += mo; outp += mo;
  int c0 = blockIdx.x * 32, r0 = blockIdx.y * 32;
#pragma unroll
  for (int i = threadIdx.y; i < 32; i += 8)
    tile[i][threadIdx.x] = in[(size_t)(r0 + i) * C + c0 + threadIdx.x];
  __syncthreads();
#pragma unroll
  for (int i = threadIdx.y; i < 32; i += 8)
    outp[(size_t)(c0 + i) * R + r0 + threadIdx.x] = (f16)tile[threadIdx.x][i];
}

// 4 rows per block, one wave per row.  grid = 512
__global__ __launch_bounds__(256) void k_embed_ln(const int* __restrict__ idx,
    const float* __restrict__ emb, f16* __restrict__ inp) {
  int r = blockIdx.x * 4 + (threadIdx.x >> 6);
  int lane = threadIdx.x & 63;
  const float* e = emb + (size_t)idx[r] * D_ + lane * 8;
  f32x4 e0 = *(const f32x4*)e;
  f32x4 e1 = *(const f32x4*)(e + 4);
  float v[8];
#pragma unroll
  for (int i = 0; i < 4; ++i) { v[i] = e0[i]; v[i + 4] = e1[i]; }
  float s = 0.f;
#pragma unroll
  for (int i = 0; i < 8; ++i) s += v[i];
  float mean = wave_sum(s) * (1.f / 512.f);
  float q = 0.f;
#pragma unroll
  for (int i = 0; i < 8; ++i) { v[i] -= mean; q += v[i] * v[i]; }
  float rs = rsqrtf(wave_sum(q) * (1.f / 512.f) + 1e-5f);
  f16x8 ov;
#pragma unroll
  for (int i = 0; i < 8; ++i) ov[i] = (f16)(v[i] * rs);
  *(f16x8*)(inp + (size_t)r * D_ + lane * 8) = ov;
}

__global__ __launch_bounds__(256) void k_init(const float* __restrict__ hi,
    const float* __restrict__ li, f16* __restrict__ zH, f16* __restrict__ zL) {
  size_t i = (size_t)blockIdx.x * 256 + threadIdx.x;
  zH[i] = (f16)hi[i & (D_ - 1)];
  zL[i] = (f16)li[i & (D_ - 1)];
}

// xi = LN(x + a1 (+ a2)) -> f16 xi and f16 xiT (B,D,T).  grid = 512
__global__ __launch_bounds__(256) void k_ln_xi(const f16* __restrict__ x,
    const f16* __restrict__ a1, const f16* __restrict__ a2,
    f16* __restrict__ xi, f16* __restrict__ xiT) {
  int r = blockIdx.x * 4 + (threadIdx.x >> 6);
  int lane = threadIdx.x & 63;
  size_t o = (size_t)r * D_ + lane * 8;
  f16x8 xv = *(const f16x8*)(x + o);
  f16x8 av = *(const f16x8*)(a1 + o);
  float v[8];
#pragma unroll
  for (int i = 0; i < 8; ++i) v[i] = (float)xv[i] + (float)av[i];
  if (a2) {
    f16x8 bv = *(const f16x8*)(a2 + o);
#pragma unroll
    for (int i = 0; i < 8; ++i) v[i] += (float)bv[i];
  }
  float s = 0.f;
#pragma unroll
  for (int i = 0; i < 8; ++i) s += v[i];
  float mean = wave_sum(s) * (1.f / 512.f);
  float q = 0.f;
#pragma unroll
  for (int i = 0; i < 8; ++i) { v[i] -= mean; q += v[i] * v[i]; }
  float rs = rsqrtf(wave_sum(q) * (1.f / 512.f) + 1e-5f);
  f16x8 ov;
#pragma unroll
  for (int i = 0; i < 8; ++i) ov[i] = (f16)(v[i] * rs);
  *(f16x8*)(xi + o) = ov;
  int b = r >> 9, t = r & (TT_ - 1);
  int d0 = lane * 8;
#pragma unroll
  for (int i = 0; i < 8; ++i)
    xiT[((size_t)b * D_ + d0 + i) * TT_ + t] = ov[i];
}

// row LN f16->f16.  grid = 4096 (16384 rows / 4)
__global__ __launch_bounds__(256) void k_ln_rows(const f16* __restrict__ in, f16* __restrict__ outp) {
  int r = blockIdx.x * 4 + (threadIdx.x >> 6);
  int lane = threadIdx.x & 63;
  size_t o = (size_t)r * D_ + lane * 8;
  f16x8 xv = *(const f16x8*)(in + o);
  float v[8];
#pragma unroll
  for (int i = 0; i < 8; ++i) v[i] = (float)xv[i];
  float s = 0.f;
#pragma unroll
  for (int i = 0; i < 8; ++i) s += v[i];
  float mean = wave_sum(s) * (1.f / 512.f);
  float q = 0.f;
#pragma unroll
  for (int i = 0; i < 8; ++i) { v[i] -= mean; q += v[i] * v[i]; }
  float rs = rsqrtf(wave_sum(q) * (1.f / 512.f) + 1e-5f);
  f16x8 ov;
#pragma unroll
  for (int i = 0; i < 8; ++i) ov[i] = (f16)(v[i] * rs);
  *(f16x8*)(outp + o) = ov;
}

// z = LN(z + LN(sum_h ypart[h])).  grid = 512
__global__ __launch_bounds__(256) void k_ln_y_out(const f16* __restrict__ ypart,
    f16* __restrict__ z) {
  int r = blockIdx.x * 4 + (threadIdx.x >> 6);
  int lane = threadIdx.x & 63;
  size_t o = (size_t)r * D_ + lane * 8;
  float v[8] = {};
#pragma unroll
  for (int k = 0; k < 8; ++k) {
    f16x8 p = *(const f16x8*)(ypart + (size_t)k * BT_ * D_ + o);
#pragma unroll
    for (int i = 0; i < 8; ++i) v[i] += (float)p[i];
  }
  float s = 0.f;
#pragma unroll
  for (int i = 0; i < 8; ++i) s += v[i];
  float mean = wave_sum(s) * (1.f / 512.f);
  float q = 0.f;
#pragma unroll
  for (int i = 0; i < 8; ++i) { v[i] -= mean; q += v[i] * v[i]; }
  float rs = rsqrtf(wave_sum(q) * (1.f / 512.f) + 1e-5f);
  f16x8 zv = *(const f16x8*)(z + o);
#pragma unroll
  for (int i = 0; i < 8; ++i) v[i] = (float)zv[i] + v[i] * rs;
  s = 0.f;
#pragma unroll
  for (int i = 0; i < 8; ++i) s += v[i];
  mean = wave_sum(s) * (1.f / 512.f);
  q = 0.f;
#pragma unroll
  for (int i = 0; i < 8; ++i) { v[i] -= mean; q += v[i] * v[i]; }
  rs = rsqrtf(wave_sum(q) * (1.f / 512.f) + 1e-5f);
  f16x8 ov;
#pragma unroll
  for (int i = 0; i < 8; ++i) ov[i] = (f16)(v[i] * rs);
  *(f16x8*)(z + o) = ov;
}

// ===================== host =====================

extern "C" void kernel_launch(void* const* d_in, const int* in_sizes, int n_in,
                              void* d_out, int out_size, void* d_ws, size_t ws_size,
                              hipStream_t stream) {
  (void)in_sizes; (void)n_in; (void)out_size;
  const int*   idx    = (const int*)  d_in[0];
  const float* emb    = (const float*)d_in[1];
  const float* h_enc  = (const float*)d_in[2];
  const float* h_encv = (const float*)d_in[3];
  const float* h_dec  = (const float*)d_in[4];
  const float* l_enc  = (const float*)d_in[5];
  const float* l_encv = (const float*)d_in[6];
  const float* l_dec  = (const float*)d_in[7];
  const float* lm     = (const float*)d_in[8];
  const float* h_init = (const float*)d_in[9];
  const float* l_init = (const float*)d_in[10];
  float* out = (float*)d_out;

  bool resident = ws_size >= ((size_t)352 << 20);

  char* w = (char*)d_ws;
  size_t off = 0;
  auto alloc = [&](size_t n) { void* p = w + off; off += (n + 255) & ~(size_t)255; return p; };
  f16* csT = (f16*)alloc(8388608);       // (T,N) packed (cos,sin) f16 pairs
  f16 *encT[2], *encvT[2], *decT[2], *lmT;
  if (resident) {
    for (int s = 0; s < 2; ++s) {
      encT[s]  = (f16*)alloc(33554432);
      encvT[s] = (f16*)alloc(33554432);
      decT[s]  = (f16*)alloc(33554432);
    }
    lmT = (f16*)alloc(8388608);
  } else {
    encT[0]  = encT[1]  = (f16*)alloc(33554432);   // shared, re-transposed on switch
    encvT[0] = encvT[1] = (f16*)alloc(33554432);
    decT[0]  = decT[1]  = (f16*)alloc(33554432);
    lmT = encT[0];                                  // reused after last encT use
  }
  f16* inp    = (f16*)alloc(2097152);
  f16* zH     = (f16*)alloc(2097152);
  f16* zL     = (f16*)alloc(2097152);
  f16* xi_bf  = (f16*)alloc(2097152);
  f16* xiT_bf = (f16*)alloc(2097152);
  f16* qrxy   = (f16*)alloc(134217728);  // qr, overwritten in place by xy

  // d_out (67.1MB) as scratch until the final logits GEMM overwrites it:
  f16* scoresB = (f16*)d_out;                      // 16.8MB
  f16* attnP   = (f16*)((char*)d_out + 16777216);  // 16.8MB (time-shared with ypart)
  f16* ypart   = attnP;                            // 8 x (2048x512) f16 head-split partials
  f16* ykv     = (f16*)((char*)d_out + 33554432);  // 16.8MB

  dim3 tb(32, 8);
  auto transpose_set = [&](int sel) {
    const float* e  = sel ? h_enc  : l_enc;
    const float* ev = sel ? h_encv : l_encv;
    const float* dc = sel ? h_dec  : l_dec;
    k_transpose<<<dim3(128, 16, 8), tb, 0, stream>>>(e,  encT[sel],  512, 4096);
    k_transpose<<<dim3(128, 16, 8), tb, 0, stream>>>(ev, encvT[sel], 512, 4096);
    k_transpose<<<dim3(16, 1024, 1), tb, 0, stream>>>(dc, decT[sel], 32768, 512);
  };

  k_tables<<<8192, 256, 0, stream>>>(csT);
  k_embed_ln<<<512, 256, 0, stream>>>(idx, emb, inp);
  k_init<<<4096, 256, 0, stream>>>(h_init, l_init, zH, zL);
  if (resident) {
    transpose_set(0);
    transpose_set(1);
    k_transpose<<<dim3(256, 16, 1), tb, 0, stream>>>(lm, lmT, 512, 8192);
  }

  int cur = -1;
  auto setw = [&](int sel) {
    if (resident || cur == sel) { cur = sel; return; }
    cur = sel;
    transpose_set(sel);
  };

  auto run_block = [&](f16* zx, const f16* a1, const f16* a2, int s) {
    k_ln_xi<<<512, 256, 0, stream>>>(zx, a1, a2, xi_bf, xiT_bf);
    k_gemm_xs<<<4096, 256, 0, stream>>>(xi_bf, encT[s], csT, qrxy);
    k_gemm_scores<<<320, 256, 0, stream>>>(qrxy, scoresB);
    k_gemm_attn<<<512, 256, 0, stream>>>(scoresB, xiT_bf, attnP);
    k_ln_rows<<<4096, 256, 0, stream>>>(attnP, ykv);
    k_gemm_xy<<<4096, 256, 0, stream>>>(ykv, encvT[s], csT, qrxy);
    k_gemm_ydec<<<512, 256, 0, stream>>>(qrxy, decT[s], ypart);
    k_ln_y_out<<<512, 256, 0, stream>>>(ypart, zx);
  };

  for (int i = 0; i < 3; ++i) {
    setw(0);
    run_block(zL, inp, zH, 0);
    run_block(zL, inp, zH, 0);
    setw(1);
    run_block(zH, zL, (const f16*)nullptr, 1);
  }
  if (!resident)  // lm_head transpose into the now-dead encT buffer
    k_transpose<<<dim3(256, 16, 1), tb, 0, stream>>>(lm, lmT, 512, 8192);
  k_gemm_logits<<<1024, 256, 0, stream>>>(zH, lmT, out);
}

// Round 16
// 3948.174 us; speedup vs baseline: 1.2055x; 1.2055x over previous
//
#include <hip/hip_runtime.h>

typedef _Float16 f16;
typedef __attribute__((ext_vector_type(8))) _Float16 f16x8;
typedef __attribute__((ext_vector_type(4))) float f32x4;
typedef __attribute__((ext_vector_type(4))) int i32x4;

#define D_  512
#define NH_ 8
#define NS_ 4096
#define TT_ 512
#define BB_ 4
#define VV_ 8192
#define HN_ 32768
#define BT_ 2048

// ===================== shared GEMM core (round-6 verified, FINAL) ===========
// C(128x128) = A(128xK) * B(128xK)^T ; 256 thr = 4 waves 2x2, 4x4 frags of
// 16x16x32 MFMA.  sync; stage(global_load_lds 16B, src chunk g^(row&7),
// linear LDS dest); sync; compute(XOR'd ds_read_b128).  LDS 32KB, 0 bank
// conflicts, ~4 blocks/CU.  Epilogue orientation: lane-adjacent axis =
// output-contiguous columns (wave-coalesced 32B segments) — R15's per-lane
// vectorized swap scattered lanes across rows and cost +63% HBM traffic.
// Exhausted (all slower): dbuf64K(R7), bounds5(R8), 128x256(R9),
// A-direct(R10), 256sq(R11), splitK(R12), dbuf-BK32(R13), op-swap(R15).

__device__ __forceinline__ void gl16(const void* g, void* l) {
  __builtin_amdgcn_global_load_lds((const __attribute__((address_space(1))) void*)g,
                                   (__attribute__((address_space(3))) void*)l, 16, 0, 0);
}

__device__ __forceinline__ void gemm_core(const f16* __restrict__ A, const f16* __restrict__ B,
    int lda, int ldb, int nk, char* As, char* Bs, f32x4 acc[4][4]) {
  int tid = threadIdx.x;
  int l = tid & 63, wid = tid >> 6;
  int wm = wid >> 1, wn = wid & 1;
  int row0 = tid >> 3, g0 = tid & 7;
  for (int kt = 0; kt < nk; ++kt) {
    __syncthreads();                       // prev tile fully consumed
#pragma unroll
    for (int it = 0; it < 4; ++it) {
      int row = row0 + 32 * it;
      int gs = g0 ^ (row & 7);             // inverse-swizzled source chunk
      int wb = (wid * 64 + it * 256) * 16; // wave-uniform linear LDS base
      gl16(A + (size_t)row * lda + gs * 8, As + wb);
      gl16(B + (size_t)row * ldb + gs * 8, Bs + wb);
    }
    __syncthreads();                       // vmcnt(0)+lgkm drain + barrier
    A += 64; B += 64;
#pragma unroll
    for (int kh = 0; kh < 2; ++kh) {
      f16x8 af[4], bfr[4];
#pragma unroll
      for (int m = 0; m < 4; ++m) {
        int row = wm * 64 + m * 16 + (l & 15);
        af[m] = *(const f16x8*)(As + row * 128 + ((kh * 64 + (l >> 4) * 16) ^ ((row & 7) << 4)));
      }
#pragma unroll
      for (int n = 0; n < 4; ++n) {
        int row = wn * 64 + n * 16 + (l & 15);
        bfr[n] = *(const f16x8*)(Bs + row * 128 + ((kh * 64 + (l >> 4) * 16) ^ ((row & 7) << 4)));
      }
#pragma unroll
      for (int m = 0; m < 4; ++m)
#pragma unroll
        for (int n = 0; n < 4; ++n)
          acc[m][n] = __builtin_amdgcn_mfma_f32_16x16x32_f16(af[m], bfr[n], acc[m][n], 0, 0, 0);
    }
  }
}

// ===================== GEMM wrappers =====================

// 1) qr = rope(relu(xi @ enc)).  nwg = 4096  (r6 mapping)
__global__ __launch_bounds__(256, 4) void k_gemm_xs(
    const f16* __restrict__ xi, const f16* __restrict__ encT,
    const f16* __restrict__ csT, f16* __restrict__ qr) {
  __shared__ i32x4 As4[1024], Bs4[1024];
  int bid = blockIdx.x;
  int swz = (bid & 7) * 512 + (bid >> 3);
  int mt = swz & 15, nt = (swz >> 4) & 31, h = swz >> 9;
  const f16* A = xi + (size_t)mt * 128 * D_;
  const f16* B = encT + ((size_t)h * NS_ + nt * 128) * D_;
  f32x4 acc[4][4] = {};
  gemm_core(A, B, D_, D_, D_ / 64, (char*)As4, (char*)Bs4, acc);
  int l = threadIdx.x & 63, wid = threadIdx.x >> 6;
  int wm = wid >> 1, wn = wid & 1;
  int r04 = (l >> 4) * 4, c0 = l & 15;
  int b = (mt * 128) >> 9;
  int tbase = (mt * 128) & (TT_ - 1);
#pragma unroll
  for (int m = 0; m < 4; ++m)
#pragma unroll
    for (int n = 0; n < 4; ++n)
#pragma unroll
      for (int r = 0; r < 4; ++r) {
        int row = wm * 64 + m * 16 + r04 + r;
        int col = wn * 64 + n * 16 + c0;
        int t = tbase + row;
        int nn = nt * 128 + col;
        float xsv = fmaxf(acc[m][n][r], 0.f);
        float prt = __shfl_xor(xsv, 1);       // partner column in adjacent lane
        int ci = 2 * (t * NS_ + nn);
        float c = (float)csT[ci], s = (float)csT[ci + 1];
        float qv = xsv * c + ((nn & 1) ? prt : -prt) * s;
        size_t o = (((size_t)b * NH_ + h) * TT_ + t) * NS_ + nn;
        qr[o] = (f16)qv;
      }
}

// 2) scores = tril_strict(QR @ QR^T) * N^-0.5.  nwg = 320  (r6 mapping)
__global__ __launch_bounds__(256, 4) void k_gemm_scores(
    const f16* __restrict__ qr, f16* __restrict__ scores) {
  __shared__ i32x4 As4[1024], Bs4[1024];
  int bid = blockIdx.x;
  int swz = (bid & 7) * 40 + (bid >> 3);
  int x = swz % 10, z = swz / 10;
  int mt = (x >= 6) ? 3 : (x >= 3) ? 2 : (x >= 1) ? 1 : 0;
  int nt = x - mt * (mt + 1) / 2;
  const f16* base = qr + (size_t)z * TT_ * NS_;
  const f16* A = base + (size_t)mt * 128 * NS_;
  const f16* B = base + (size_t)nt * 128 * NS_;
  f32x4 acc[4][4] = {};
  gemm_core(A, B, NS_, NS_, NS_ / 64, (char*)As4, (char*)Bs4, acc);
  int l = threadIdx.x & 63, wid = threadIdx.x >> 6;
  int wm = wid >> 1, wn = wid & 1;
  int r04 = (l >> 4) * 4, c0 = l & 15;
  f16* outp = scores + (size_t)z * TT_ * TT_;
#pragma unroll
  for (int m = 0; m < 4; ++m)
#pragma unroll
    for (int n = 0; n < 4; ++n)
#pragma unroll
      for (int r = 0; r < 4; ++r) {
        int t = mt * 128 + wm * 64 + m * 16 + r04 + r;
        int s_ = nt * 128 + wn * 64 + n * 16 + c0;
        float v = (t > s_) ? acc[m][n][r] * 0.015625f : 0.f;
        outp[(size_t)t * TT_ + s_] = (f16)v;
      }
}

// 3) attn = scores @ xi (via xiT), f16 out.  nwg = 512, K-tiles = 2*mt+2
__global__ __launch_bounds__(256, 4) void k_gemm_attn(
    const f16* __restrict__ scores, const f16* __restrict__ xiT, f16* __restrict__ attn) {
  __shared__ i32x4 As4[1024], Bs4[1024];
  int bid = blockIdx.x;
  int swz = (bid & 7) * 64 + (bid >> 3);
  int mt = swz & 3, ntd = (swz >> 2) & 3, z = swz >> 4;
  int b = z >> 3;
  const f16* A = scores + (size_t)z * TT_ * TT_ + (size_t)mt * 128 * TT_;
  const f16* B = xiT + (size_t)b * D_ * TT_ + (size_t)ntd * 128 * TT_;
  f32x4 acc[4][4] = {};
  gemm_core(A, B, TT_, TT_, 2 * mt + 2, (char*)As4, (char*)Bs4, acc);
  int l = threadIdx.x & 63, wid = threadIdx.x >> 6;
  int wm = wid >> 1, wn = wid & 1;
  int r04 = (l >> 4) * 4, c0 = l & 15;
#pragma unroll
  for (int m = 0; m < 4; ++m)
#pragma unroll
    for (int n = 0; n < 4; ++n)
#pragma unroll
      for (int r = 0; r < 4; ++r) {
        int t = mt * 128 + wm * 64 + m * 16 + r04 + r;
        int d = ntd * 128 + wn * 64 + n * 16 + c0;
        attn[((size_t)z * TT_ + t) * D_ + d] = (f16)acc[m][n][r];
      }
}

// 4) xy = xs * relu(yKV @ enc_v); xs via inverse rope from qr, in-place RMW.
//    nwg = 4096.  R8's h-pinned XCD mapping (encvT[h] slab stays L2-resident).
__global__ __launch_bounds__(256, 4) void k_gemm_xy(
    const f16* __restrict__ ykv, const f16* __restrict__ encvT,
    const f16* __restrict__ csT, f16* __restrict__ qrxy) {
  __shared__ i32x4 As4[1024], Bs4[1024];
  int bid = blockIdx.x;
  int xcd = bid & 7, k = bid >> 3;            // k in 0..511
  int h = xcd, b = k >> 7, nt = (k >> 2) & 31, mt = k & 3;
  int z = b * NH_ + h;
  const f16* A = ykv + (size_t)z * TT_ * D_ + (size_t)mt * 128 * D_;
  const f16* B = encvT + ((size_t)h * NS_ + nt * 128) * D_;
  f32x4 acc[4][4] = {};
  gemm_core(A, B, D_, D_, D_ / 64, (char*)As4, (char*)Bs4, acc);
  int l = threadIdx.x & 63, wid = threadIdx.x >> 6;
  int wm = wid >> 1, wn = wid & 1;
  int r04 = (l >> 4) * 4, c0 = l & 15;
#pragma unroll
  for (int m = 0; m < 4; ++m)
#pragma unroll
    for (int n = 0; n < 4; ++n)
#pragma unroll
      for (int r = 0; r < 4; ++r) {
        int t = mt * 128 + wm * 64 + m * 16 + r04 + r;
        int nn = nt * 128 + wn * 64 + n * 16 + c0;
        float ys = fmaxf(acc[m][n][r], 0.f);
        size_t o = ((size_t)z * TT_ + t) * NS_ + nn;
        float qv = (float)qrxy[o];
        float prt = __shfl_xor(qv, 1);
        int ci = 2 * (t * NS_ + nn);
        float c = (float)csT[ci], s = (float)csT[ci + 1];
        float xsv = (nn & 1) ? (qv * c - prt * s) : (qv * c + prt * s);
        qrxy[o] = (f16)(xsv * ys);
      }
}

// 5) ypart[h] = xy_h @ dec_h (K split by head), f16 out.  nwg = 512  (r6)
__global__ __launch_bounds__(256, 4) void k_gemm_ydec(
    const f16* __restrict__ xy, const f16* __restrict__ decT, f16* __restrict__ ypart) {
  __shared__ i32x4 As4[1024], Bs4[1024];
  int bid = blockIdx.x;
  int swz = (bid & 7) * 64 + (bid >> 3);
  int mt = swz & 15, nt = (swz >> 4) & 3, kz = swz >> 6;
  int b = mt >> 2, t0 = (mt & 3) * 128;
  const f16* A = xy + ((size_t)(b * NH_ + kz) * TT_ + t0) * NS_;
  const f16* B = decT + (size_t)nt * 128 * HN_ + (size_t)kz * NS_;
  f32x4 acc[4][4] = {};
  gemm_core(A, B, NS_, HN_, NS_ / 64, (char*)As4, (char*)Bs4, acc);
  int l = threadIdx.x & 63, wid = threadIdx.x >> 6;
  int wm = wid >> 1, wn = wid & 1;
  int r04 = (l >> 4) * 4, c0 = l & 15;
  f16* outp = ypart + (size_t)kz * BT_ * D_;
#pragma unroll
  for (int m = 0; m < 4; ++m)
#pragma unroll
    for (int n = 0; n < 4; ++n)
#pragma unroll
      for (int r = 0; r < 4; ++r) {
        int R = mt * 128 + wm * 64 + m * 16 + r04 + r;
        int c = nt * 128 + wn * 64 + n * 16 + c0;
        outp[(size_t)R * D_ + c] = (f16)acc[m][n][r];
      }
}

// 6) logits = zH @ lm_head.  nwg = 1024  (r6)
__global__ __launch_bounds__(256, 4) void k_gemm_logits(
    const f16* __restrict__ zbf, const f16* __restrict__ lmT, float* __restrict__ outp) {
  __shared__ i32x4 As4[1024], Bs4[1024];
  int bid = blockIdx.x;
  int swz = (bid & 7) * 128 + (bid >> 3);
  int mt = swz & 15, nt = swz >> 4;
  const f16* A = zbf + (size_t)mt * 128 * D_;
  const f16* B = lmT + (size_t)nt * 128 * D_;
  f32x4 acc[4][4] = {};
  gemm_core(A, B, D_, D_, D_ / 64, (char*)As4, (char*)Bs4, acc);
  int l = threadIdx.x & 63, wid = threadIdx.x >> 6;
  int wm = wid >> 1, wn = wid & 1;
  int r04 = (l >> 4) * 4, c0 = l & 15;
#pragma unroll
  for (int m = 0; m < 4; ++m)
#pragma unroll
    for (int n = 0; n < 4; ++n)
#pragma unroll
      for (int r = 0; r < 4; ++r) {
        int R = mt * 128 + wm * 64 + m * 16 + r04 + r;
        int v = nt * 128 + wn * 64 + n * 16 + c0;
        outp[(size_t)R * VV_ + v] = acc[m][n][r];
      }
}

// ===================== LN / elementwise (wave-per-row, vectorized) ==========

__device__ __forceinline__ float wave_sum(float v) {
#pragma unroll
  for (int o = 32; o > 0; o >>= 1) v += __shfl_xor(v, o);
  return v;
}

__global__ __launch_bounds__(256) void k_tables(f16* __restrict__ csT) {
  int i = blockIdx.x * 256 + threadIdx.x;
  int t = i >> 12, n = i & (NS_ - 1);
  float q = (float)(n & ~1);
  float freq = exp2f(-16.f * q / 4096.f) * 0.15915494309189535f; // 1/(2pi)
  float ph = (float)t * freq;
  ph -= floorf(ph);
  float ang = ph * 6.283185307179586f;
  csT[2 * i]     = (f16)cosf(ang);
  csT[2 * i + 1] = (f16)sinf(ang);
}

__global__ void k_transpose(const float* __restrict__ in, f16* __restrict__ outp, int R, int C) {
  __shared__ float tile[32][33];
  size_t mo = (size_t)blockIdx.z * R * C;
  in += mo; outp += mo;
  int c0 = blockIdx.x * 32, r0 = blockIdx.y * 32;
#pragma unroll
  for (int i = threadIdx.y; i < 32; i += 8)
    tile[i][threadIdx.x] = in[(size_t)(r0 + i) * C + c0 + threadIdx.x];
  __syncthreads();
#pragma unroll
  for (int i = threadIdx.y; i < 32; i += 8)
    outp[(size_t)(c0 + i) * R + r0 + threadIdx.x] = (f16)tile[threadIdx.x][i];
}

// 4 rows per block, one wave per row.  grid = 512
__global__ __launch_bounds__(256) void k_embed_ln(const int* __restrict__ idx,
    const float* __restrict__ emb, f16* __restrict__ inp) {
  int r = blockIdx.x * 4 + (threadIdx.x >> 6);
  int lane = threadIdx.x & 63;
  const float* e = emb + (size_t)idx[r] * D_ + lane * 8;
  f32x4 e0 = *(const f32x4*)e;
  f32x4 e1 = *(const f32x4*)(e + 4);
  float v[8];
#pragma unroll
  for (int i = 0; i < 4; ++i) { v[i] = e0[i]; v[i + 4] = e1[i]; }
  float s = 0.f;
#pragma unroll
  for (int i = 0; i < 8; ++i) s += v[i];
  float mean = wave_sum(s) * (1.f / 512.f);
  float q = 0.f;
#pragma unroll
  for (int i = 0; i < 8; ++i) { v[i] -= mean; q += v[i] * v[i]; }
  float rs = rsqrtf(wave_sum(q) * (1.f / 512.f) + 1e-5f);
  f16x8 ov;
#pragma unroll
  for (int i = 0; i < 8; ++i) ov[i] = (f16)(v[i] * rs);
  *(f16x8*)(inp + (size_t)r * D_ + lane * 8) = ov;
}

__global__ __launch_bounds__(256) void k_init(const float* __restrict__ hi,
    const float* __restrict__ li, f16* __restrict__ zH, f16* __restrict__ zL) {
  size_t i = (size_t)blockIdx.x * 256 + threadIdx.x;
  zH[i] = (f16)hi[i & (D_ - 1)];
  zL[i] = (f16)li[i & (D_ - 1)];
}

// xi = LN(x + a1 (+ a2)) -> f16 xi and f16 xiT (B,D,T).  grid = 512
__global__ __launch_bounds__(256) void k_ln_xi(const f16* __restrict__ x,
    const f16* __restrict__ a1, const f16* __restrict__ a2,
    f16* __restrict__ xi, f16* __restrict__ xiT) {
  int r = blockIdx.x * 4 + (threadIdx.x >> 6);
  int lane = threadIdx.x & 63;
  size_t o = (size_t)r * D_ + lane * 8;
  f16x8 xv = *(const f16x8*)(x + o);
  f16x8 av = *(const f16x8*)(a1 + o);
  float v[8];
#pragma unroll
  for (int i = 0; i < 8; ++i) v[i] = (float)xv[i] + (float)av[i];
  if (a2) {
    f16x8 bv = *(const f16x8*)(a2 + o);
#pragma unroll
    for (int i = 0; i < 8; ++i) v[i] += (float)bv[i];
  }
  float s = 0.f;
#pragma unroll
  for (int i = 0; i < 8; ++i) s += v[i];
  float mean = wave_sum(s) * (1.f / 512.f);
  float q = 0.f;
#pragma unroll
  for (int i = 0; i < 8; ++i) { v[i] -= mean; q += v[i] * v[i]; }
  float rs = rsqrtf(wave_sum(q) * (1.f / 512.f) + 1e-5f);
  f16x8 ov;
#pragma unroll
  for (int i = 0; i < 8; ++i) ov[i] = (f16)(v[i] * rs);
  *(f16x8*)(xi + o) = ov;
  int b = r >> 9, t = r & (TT_ - 1);
  int d0 = lane * 8;
#pragma unroll
  for (int i = 0; i < 8; ++i)
    xiT[((size_t)b * D_ + d0 + i) * TT_ + t] = ov[i];
}

// row LN f16->f16.  grid = 4096 (16384 rows / 4)
__global__ __launch_bounds__(256) void k_ln_rows(const f16* __restrict__ in, f16* __restrict__ outp) {
  int r = blockIdx.x * 4 + (threadIdx.x >> 6);
  int lane = threadIdx.x & 63;
  size_t o = (size_t)r * D_ + lane * 8;
  f16x8 xv = *(const f16x8*)(in + o);
  float v[8];
#pragma unroll
  for (int i = 0; i < 8; ++i) v[i] = (float)xv[i];
  float s = 0.f;
#pragma unroll
  for (int i = 0; i < 8; ++i) s += v[i];
  float mean = wave_sum(s) * (1.f / 512.f);
  float q = 0.f;
#pragma unroll
  for (int i = 0; i < 8; ++i) { v[i] -= mean; q += v[i] * v[i]; }
  float rs = rsqrtf(wave_sum(q) * (1.f / 512.f) + 1e-5f);
  f16x8 ov;
#pragma unroll
  for (int i = 0; i < 8; ++i) ov[i] = (f16)(v[i] * rs);
  *(f16x8*)(outp + o) = ov;
}

// z = LN(z + LN(sum_h ypart[h])).  grid = 512
__global__ __launch_bounds__(256) void k_ln_y_out(const f16* __restrict__ ypart,
    f16* __restrict__ z) {
  int r = blockIdx.x * 4 + (threadIdx.x >> 6);
  int lane = threadIdx.x & 63;
  size_t o = (size_t)r * D_ + lane * 8;
  float v[8] = {};
#pragma unroll
  for (int k = 0; k < 8; ++k) {
    f16x8 p = *(const f16x8*)(ypart + (size_t)k * BT_ * D_ + o);
#pragma unroll
    for (int i = 0; i < 8; ++i) v[i] += (float)p[i];
  }
  float s = 0.f;
#pragma unroll
  for (int i = 0; i < 8; ++i) s += v[i];
  float mean = wave_sum(s) * (1.f / 512.f);
  float q = 0.f;
#pragma unroll
  for (int i = 0; i < 8; ++i) { v[i] -= mean; q += v[i] * v[i]; }
  float rs = rsqrtf(wave_sum(q) * (1.f / 512.f) + 1e-5f);
  f16x8 zv = *(const f16x8*)(z + o);
#pragma unroll
  for (int i = 0; i < 8; ++i) v[i] = (float)zv[i] + v[i] * rs;
  s = 0.f;
#pragma unroll
  for (int i = 0; i < 8; ++i) s += v[i];
  mean = wave_sum(s) * (1.f / 512.f);
  q = 0.f;
#pragma unroll
  for (int i = 0; i < 8; ++i) { v[i] -= mean; q += v[i] * v[i]; }
  rs = rsqrtf(wave_sum(q) * (1.f / 512.f) + 1e-5f);
  f16x8 ov;
#pragma unroll
  for (int i = 0; i < 8; ++i) ov[i] = (f16)(v[i] * rs);
  *(f16x8*)(z + o) = ov;
}

// ===================== host =====================

extern "C" void kernel_launch(void* const* d_in, const int* in_sizes, int n_in,
                              void* d_out, int out_size, void* d_ws, size_t ws_size,
                              hipStream_t stream) {
  (void)in_sizes; (void)n_in; (void)out_size;
  const int*   idx    = (const int*)  d_in[0];
  const float* emb    = (const float*)d_in[1];
  const float* h_enc  = (const float*)d_in[2];
  const float* h_encv = (const float*)d_in[3];
  const float* h_dec  = (const float*)d_in[4];
  const float* l_enc  = (const float*)d_in[5];
  const float* l_encv = (const float*)d_in[6];
  const float* l_dec  = (const float*)d_in[7];
  const float* lm     = (const float*)d_in[8];
  const float* h_init = (const float*)d_in[9];
  const float* l_init = (const float*)d_in[10];
  float* out = (float*)d_out;

  bool resident = ws_size >= ((size_t)352 << 20);

  char* w = (char*)d_ws;
  size_t off = 0;
  auto alloc = [&](size_t n) { void* p = w + off; off += (n + 255) & ~(size_t)255; return p; };
  f16* csT = (f16*)alloc(8388608);       // (T,N) packed (cos,sin) f16 pairs
  f16 *encT[2], *encvT[2], *decT[2], *lmT;
  if (resident) {
    for (int s = 0; s < 2; ++s) {
      encT[s]  = (f16*)alloc(33554432);
      encvT[s] = (f16*)alloc(33554432);
      decT[s]  = (f16*)alloc(33554432);
    }
    lmT = (f16*)alloc(8388608);
  } else {
    encT[0]  = encT[1]  = (f16*)alloc(33554432);   // shared, re-transposed on switch
    encvT[0] = encvT[1] = (f16*)alloc(33554432);
    decT[0]  = decT[1]  = (f16*)alloc(33554432);
    lmT = encT[0];                                  // reused after last encT use
  }
  f16* inp    = (f16*)alloc(2097152);
  f16* zH     = (f16*)alloc(2097152);
  f16* zL     = (f16*)alloc(2097152);
  f16* xi_bf  = (f16*)alloc(2097152);
  f16* xiT_bf = (f16*)alloc(2097152);
  f16* qrxy   = (f16*)alloc(134217728);  // qr, overwritten in place by xy

  // d_out (67.1MB) as scratch until the final logits GEMM overwrites it:
  f16* scoresB = (f16*)d_out;                      // 16.8MB
  f16* attnP   = (f16*)((char*)d_out + 16777216);  // 16.8MB (time-shared with ypart)
  f16* ypart   = attnP;                            // 8 x (2048x512) f16 head-split partials
  f16* ykv     = (f16*)((char*)d_out + 33554432);  // 16.8MB

  dim3 tb(32, 8);
  auto transpose_set = [&](int sel) {
    const float* e  = sel ? h_enc  : l_enc;
    const float* ev = sel ? h_encv : l_encv;
    const float* dc = sel ? h_dec  : l_dec;
    k_transpose<<<dim3(128, 16, 8), tb, 0, stream>>>(e,  encT[sel],  512, 4096);
    k_transpose<<<dim3(128, 16, 8), tb, 0, stream>>>(ev, encvT[sel], 512, 4096);
    k_transpose<<<dim3(16, 1024, 1), tb, 0, stream>>>(dc, decT[sel], 32768, 512);
  };

  k_tables<<<8192, 256, 0, stream>>>(csT);
  k_embed_ln<<<512, 256, 0, stream>>>(idx, emb, inp);
  k_init<<<4096, 256, 0, stream>>>(h_init, l_init, zH, zL);
  if (resident) {
    transpose_set(0);
    transpose_set(1);
    k_transpose<<<dim3(256, 16, 1), tb, 0, stream>>>(lm, lmT, 512, 8192);
  }

  int cur = -1;
  auto setw = [&](int sel) {
    if (resident || cur == sel) { cur = sel; return; }
    cur = sel;
    transpose_set(sel);
  };

  auto run_block = [&](f16* zx, const f16* a1, const f16* a2, int s) {
    k_ln_xi<<<512, 256, 0, stream>>>(zx, a1, a2, xi_bf, xiT_bf);
    k_gemm_xs<<<4096, 256, 0, stream>>>(xi_bf, encT[s], csT, qrxy);
    k_gemm_scores<<<320, 256, 0, stream>>>(qrxy, scoresB);
    k_gemm_attn<<<512, 256, 0, stream>>>(scoresB, xiT_bf, attnP);
    k_ln_rows<<<4096, 256, 0, stream>>>(attnP, ykv);
    k_gemm_xy<<<4096, 256, 0, stream>>>(ykv, encvT[s], csT, qrxy);
    k_gemm_ydec<<<512, 256, 0, stream>>>(qrxy, decT[s], ypart);
    k_ln_y_out<<<512, 256, 0, stream>>>(ypart, zx);
  };

  for (int i = 0; i < 3; ++i) {
    setw(0);
    run_block(zL, inp, zH, 0);
    run_block(zL, inp, zH, 0);
    setw(1);
    run_block(zH, zL, (const f16*)nullptr, 1);
  }
  if (!resident)  // lm_head transpose into the now-dead encT buffer
    k_transpose<<<dim3(256, 16, 1), tb, 0, stream>>>(lm, lmT, 512, 8192);
  k_gemm_logits<<<1024, 256, 0, stream>>>(zH, lmT, out);
}